// Round 10
// baseline (1880.801 us; speedup 1.0000x reference)
//
#include <hip/hip_runtime.h>
#include <hip/hip_bf16.h>

#define N_NODES 50000
#define DIM     256
#define NEXP    4
#define NLAYER  3
#define NEDGE   1600000
#define BN_EPS  1e-5f

typedef __attribute__((ext_vector_type(8))) short          s16x8;
typedef __attribute__((ext_vector_type(8))) unsigned short u16x8;
typedef __attribute__((ext_vector_type(4))) float          f32x4;

// ---------------------------------------------------------------- utilities
static __device__ __forceinline__ float wave_reduce(float v) {
    #pragma unroll
    for (int off = 32; off; off >>= 1) v += __shfl_xor(v, off, 64);
    return v;
}

// split f32 into bf16 hi + bf16 lo (RNE); x ≈ hi + lo with |resid| <= 2^-18 |x|
static __device__ __forceinline__ void bf16split(float x, unsigned short& hi,
                                                 unsigned short& lo) {
    unsigned xb = __float_as_uint(x);
    unsigned hb = (xb + 0x7FFFu + ((xb >> 16) & 1u)) & 0xFFFF0000u;
    float hif = __uint_as_float(hb);
    float l  = x - hif;                       // exact (Sterbenz)
    unsigned lb2 = __float_as_uint(l);
    unsigned lb  = (lb2 + 0x7FFFu + ((lb2 >> 16) & 1u)) >> 16;
    hi = (unsigned short)(hb >> 16);
    lo = (unsigned short)lb;
}

// ---------------------------------------------------------------- degrees
__global__ void k_deg(const int* __restrict__ src, const int* __restrict__ dst,
                      int* __restrict__ cnt_out, int* __restrict__ cnt_in) {
    int i = blockIdx.x * 256 + threadIdx.x;
    if (i < NEDGE) {
        atomicAdd(&cnt_out[src[i]], 1);
        atomicAdd(&cnt_in[dst[i]], 1);
    }
}

// exclusive scan of cnt_in -> offs (N+1), copy to cursor; FUSED (round-10):
// k_norm's rsqrt writes (identical formulas on identical inputs -> bit-exact)
__global__ __launch_bounds__(1024) void k_scan(const int* __restrict__ cnt_in,
                                               const int* __restrict__ cnt_out,
                                               int* __restrict__ offs,
                                               int* __restrict__ cursor,
                                               float* __restrict__ nsrc,
                                               float* __restrict__ ndst) {
    __shared__ int ps[1024];
    const int CH = 49;                       // 1024*49 = 50176 >= 50000
    int t = threadIdx.x;
    int base = t * CH;
    int s = 0;
    for (int k = 0; k < CH; k++) {
        int i = base + k;
        if (i < N_NODES) {
            int ci = cnt_in[i];
            s += ci;
            nsrc[i] = rsqrtf(fmaxf((float)cnt_out[i], 1.f));
            ndst[i] = rsqrtf(fmaxf((float)ci, 1.f));
        }
    }
    ps[t] = s; __syncthreads();
    for (int off = 1; off < 1024; off <<= 1) {
        int v = ps[t];
        int u = (t >= off) ? ps[t - off] : 0;
        __syncthreads();
        ps[t] = v + u;
        __syncthreads();
    }
    int run = (t == 0) ? 0 : ps[t - 1];
    for (int k = 0; k < CH; k++) {
        int i = base + k;
        if (i < N_NODES) { offs[i] = run; cursor[i] = run; run += cnt_in[i]; }
    }
    if (t == 1023) offs[N_NODES] = ps[1023];
}

__global__ void k_fill(const int* __restrict__ src, const int* __restrict__ dst,
                       int* __restrict__ cursor, int* __restrict__ csr_s) {
    int i = blockIdx.x * 256 + threadIdx.x;
    if (i < NEDGE) {
        int s = src[i], d = dst[i];
        int pos = atomicAdd(&cursor[d], 1);   // order varies per run -> k_agg must be
        csr_s[pos] = s;                       // order-invariant (fixed-point acc)
    }
}

// ---------------------------------------------------------------- embedding
__global__ void k_emb(const int* __restrict__ x, const float4* __restrict__ emb4,
                      float4* __restrict__ h4) {
    int i = blockIdx.x * 256 + threadIdx.x;   // N*64 float4s
    if (i < N_NODES * 64) {
        int n = i >> 6, c = i & 63;
        h4[i] = emb4[x[n] * 64 + c];
    }
}

// ---------------------------------------------------------------- gating: pid + (ga,gb) per node
// pair ids: (0,1)=0 (0,2)=1 (0,3)=2 (1,2)=3 (1,3)=4 (2,3)=5; ga = gate of lower-index expert
// ROUND-10: also zeroes gcount (block 0) — consumed 2 dispatches later (k_gram's
// bucket branch), stream order guarantees completion. Replaces the gcount memset.
__global__ void k_gate(const float4* __restrict__ h4, const float4* __restrict__ wg4,
                       int* __restrict__ pid, float* __restrict__ gaN,
                       float* __restrict__ gbN, int* __restrict__ gcount) {
    if (blockIdx.x == 0 && threadIdx.x < 6) gcount[threadIdx.x] = 0;
    int n    = blockIdx.x * 4 + (threadIdx.x >> 6);
    int lane = threadIdx.x & 63;
    if (n >= N_NODES) return;
    float4 hv = h4[n * 64 + lane];
    const float* hp = (const float*)&hv;
    float4 acc = {0.f, 0.f, 0.f, 0.f};
    #pragma unroll
    for (int j = 0; j < 4; j++) {
        float4 w = wg4[lane * 4 + j];   // w_gate[l][d][0..3]
        acc.x += hp[j] * w.x; acc.y += hp[j] * w.y;
        acc.z += hp[j] * w.z; acc.w += hp[j] * w.w;
    }
    acc.x = wave_reduce(acc.x); acc.y = wave_reduce(acc.y);
    acc.z = wave_reduce(acc.z); acc.w = wave_reduce(acc.w);
    if (lane == 0) {
        float lg[4] = {acc.x, acc.y, acc.z, acc.w};
        int e1 = 0;
        #pragma unroll
        for (int e = 1; e < 4; e++) if (lg[e] > lg[e1]) e1 = e;   // ties -> lower idx (top_k)
        int e2 = -1;
        #pragma unroll
        for (int e = 0; e < 4; e++) {
            if (e == e1) continue;
            if (e2 < 0 || lg[e] > lg[e2]) e2 = e;
        }
        float v1 = lg[e1], v2 = lg[e2];
        float g2 = 1.f / (1.f + expf(v1 - v2));   // softmax over {v1,v2}
        float g1 = 1.f - g2;
        int a = min(e1, e2), b = max(e1, e2);
        float ga = (e1 < e2) ? g1 : g2;
        float gb = (e1 < e2) ? g2 : g1;
        int p = (a == 0) ? (b - 1) : ((a == 1) ? (b + 1) : (b + 2));
        pid[n] = p; gaN[n] = ga; gbN[n] = gb;
    }
}

// ---------------------------------------------------------------- aggregation (one wave / dst)
// R0-BASELINE BODY (thrice-verified; fastest variant: ~221us, VGPR 24, occ 76%).
// k_agg floor ~220us: r4 (unroll-4: no change), r5 (f64: VALU 73->28%, no change),
// r6 (XCD-slice: 4.3x WORSE) bracket it as L3->L2 fill-path bound for this
// random gather (measured 53% L2 hit vs ~62% theoretical max for 51MB table /
// 32MB L2 — near-optimal). SINGLE-OUTPUT ONLY: adding extra outputs here fails
// deterministically (4-for-4: rounds 0,1,2,7) — any multi-output fusion into
// k_agg is BANNED.
// DETERMINISM: csr order varies per run (atomic fill). int64 fixed-point
// (quantum 2^-32) accumulate: integer addition is order-invariant -> h is
// bit-identical across runs regardless of atomic scheduling.
__global__ void k_agg(const float4* __restrict__ h4,
                      const int* __restrict__ offs,
                      const int* __restrict__ csr_s, const float* __restrict__ nsrc,
                      const float* __restrict__ ndst,
                      float4* __restrict__ agg4) {
    const float S  = 4294967296.0f;        // 2^32 (exact exponent shift on w)
    const float SI = 1.0f / 4294967296.0f;
    int n    = blockIdx.x * 4 + (threadIdx.x >> 6);
    int lane = threadIdx.x & 63;
    if (n >= N_NODES) return;
    int beg = offs[n], end = offs[n + 1];
    long long ax = 0, ay = 0, az = 0, aw = 0;
    int j = beg;
    for (; j + 1 < end; j += 2) {          // unroll-2: two independent gathers in flight
        int   s0 = csr_s[j],     s1 = csr_s[j + 1];
        float w0 = nsrc[s0] * S, w1 = nsrc[s1] * S;
        float4 a = h4[(size_t)s0 * 64 + lane];
        float4 b = h4[(size_t)s1 * 64 + lane];
        ax += (long long)(w0 * a.x) + (long long)(w1 * b.x);
        ay += (long long)(w0 * a.y) + (long long)(w1 * b.y);
        az += (long long)(w0 * a.z) + (long long)(w1 * b.z);
        aw += (long long)(w0 * a.w) + (long long)(w1 * b.w);
    }
    if (j < end) {
        int   s0 = csr_s[j];
        float w0 = nsrc[s0] * S;
        float4 a = h4[(size_t)s0 * 64 + lane];
        ax += (long long)(w0 * a.x); ay += (long long)(w0 * a.y);
        az += (long long)(w0 * a.z); aw += (long long)(w0 * a.w);
    }
    float nd = ndst[n] * SI;
    float4 o;
    o.x = nd * (float)ax; o.y = nd * (float)ay;
    o.z = nd * (float)az; o.w = nd * (float)aw;
    agg4[n * 64 + lane] = o;
}

// ---------------------------------------------------------------- Gram + pack/colsum/bucket mega-kernel
// ROUND-10 grid fusion: grid.y 10 -> 16. pr<10: Gram pair-tile blocks (verbatim
// r9 body -> Cp bit-identical). pr>=10: the r9 k_pcs body (250 blocks, CH=200,
// same mapping and add order -> msum_p/Apk bit-identical) plus k_bucket's
// two-level counting for the block's own 200-node range (bucket order varies
// per run — tolerated: k_moe output is per-node independent of tile mates).
// Saves 2 dispatch boundaries per layer (~18us each measured in r9).
#define GSL   48     // k-slices
#define GCH   1056   // rows per slice: 48*1056 = 50688 >= 50000 (multiple of 16)
#define NPAIR 10
__global__ __launch_bounds__(256) void k_gram(const float* __restrict__ agg,
                                              float* __restrict__ Cp,
                                              const int* __restrict__ pid,
                                              int* __restrict__ gcount,
                                              int* __restrict__ bnode,
                                              unsigned short* __restrict__ Apk,
                                              float* __restrict__ msum_p) {
    __shared__ float LA[16][64];
    __shared__ float LB[16][64];
    __shared__ int cnt6[6], base6[6];
    int t  = threadIdx.x;
    int pr = blockIdx.y;            // 0..9: gram pair; 10..15: pcs/bucket chunk
    if (pr >= 10) {
        int gid = blockIdx.x * 6 + (pr - 10);   // 0..287
        if (gid >= 250) return;
        const int CH = 200;                     // 250*200 = 50000 exact
        int n0 = gid * CH;
        // ---- bucket (k_bucket two-level pattern over this block's node range)
        if (t < 6) cnt6[t] = 0;
        __syncthreads();
        int p = 0, pos = 0;
        bool valid = (t < CH);
        if (valid) { p = pid[n0 + t]; pos = atomicAdd(&cnt6[p], 1); }
        __syncthreads();
        if (t < 6) base6[t] = atomicAdd(&gcount[t], cnt6[t]);
        __syncthreads();
        if (valid) bnode[p * N_NODES + base6[p] + pos] = n0 + t;
        // ---- pack + column-sum (r9 k_pcs body verbatim)
        float s = 0.f;
        for (int r = 0; r < CH; r++) {
            int n = n0 + r;
            float v = agg[(size_t)n * DIM + t];
            s += v;
            unsigned short hi, lo;
            bf16split(v, hi, lo);
            Apk[(size_t)n * 512 + t]       = hi;
            Apk[(size_t)n * 512 + 256 + t] = lo;
        }
        msum_p[gid * 256 + t] = s;
        return;
    }
    const int tiT[NPAIR] = {0,0,0,0,1,1,1,2,2,3};
    const int tjT[NPAIR] = {0,1,2,3,1,2,3,2,3,3};
    int sl = blockIdx.x;            // k-slice
    int ti = tiT[pr], tj = tjT[pr];
    int tx = t & 15, ty = t >> 4;
    float acc[4][4] = {};
    int nbase = sl * GCH;
    const float4* agg4 = (const float4*)agg;
    for (int s0 = 0; s0 < GCH; s0 += 16) {
        int r = ty;                  // 16 rows staged, one per thread group
        int n = nbase + s0 + r;
        float4 va = {0.f, 0.f, 0.f, 0.f}, vb = {0.f, 0.f, 0.f, 0.f};
        if (n < N_NODES) {
            va = agg4[n * 64 + ti * 16 + tx];
            vb = agg4[n * 64 + tj * 16 + tx];
        }
        __syncthreads();
        *(float4*)&LA[r][tx * 4] = va;
        *(float4*)&LB[r][tx * 4] = vb;
        __syncthreads();
        #pragma unroll
        for (int rr = 0; rr < 16; rr++) {
            float4 a = *(const float4*)&LA[rr][tx * 4];
            float4 b = *(const float4*)&LB[rr][ty * 4];
            const float* af = (const float*)&a;
            const float* bf = (const float*)&b;
            #pragma unroll
            for (int i = 0; i < 4; i++)
                #pragma unroll
                for (int j = 0; j < 4; j++)
                    acc[i][j] += af[i] * bf[j];
        }
    }
    float* Cb = Cp + ((size_t)(sl * NPAIR + pr)) * 4096;
    #pragma unroll
    for (int i = 0; i < 4; i++) {
        float4 v; v.x = acc[i][0]; v.y = acc[i][1]; v.z = acc[i][2]; v.w = acc[i][3];
        *(float4*)&Cb[(tx * 4 + i) * 64 + ty * 4] = v;
    }
}

// ---------------------------------------------------------------- fused reductions
// Block 0 = msumred body verbatim; blocks 1..256 = gred body verbatim with
// gid = (bid-1)*256 + t. Outputs independent; add orders unchanged -> bit-exact.
__global__ void k_red(const float* __restrict__ msum_p, float* __restrict__ msum,
                      const float* __restrict__ Cp, float* __restrict__ Cm) {
    int t = threadIdx.x;
    if (blockIdx.x == 0) {
        float s = 0.f;
        for (int b = 0; b < 250; b++) s += msum_p[b * 256 + t];
        msum[t] = s;
        return;
    }
    int gid = (blockIdx.x - 1) * 256 + t;        // 65536
    int i = gid >> 8, j = gid & 255;
    int a = i >> 6, b = j >> 6, ii = i & 63, jj = j & 63;
    int ro = ii, co = jj;
    if (a > b) { int tmp = a; a = b; b = tmp; ro = jj; co = ii; }   // symmetric reconstruct
    int pr = (a == 0) ? b : ((a == 1) ? 3 + b : ((a == 2) ? 5 + b : 6 + b));
    const float* p = Cp + (size_t)pr * 4096 + ro * 64 + co;
    float s = 0.f;
    #pragma unroll 8
    for (int sl = 0; sl < GSL; sl++) s += p[(size_t)sl * NPAIR * 4096];
    Cm[gid] = s;
}

// ---------------------------------------------------------------- BN stats -> shift + packed W
// ROUND-10: k_wscale fused in. wsh[t] = W[t][f] is already staged in LDS; after
// sg is computed it is broadcast via LDS and every thread writes
// Wpk[(e*256+f)*512 + t] = bf16split(wsh[t]*sg) — the IDENTICAL float product
// k_wscale computed (conv_W[k*256+f]*scaleb[e*256+f] with k=t) -> Wpk
// bit-identical. scaleb buffer eliminated.
__global__ __launch_bounds__(256) void k_stats(const float* __restrict__ C,
                                               const float* __restrict__ msum,
                                               const float* __restrict__ conv_W,
                                               const float* __restrict__ bn_gamma,
                                               const float* __restrict__ bn_beta,
                                               float* __restrict__ shiftb,
                                               unsigned short* __restrict__ Wpk,
                                               int l) {
    int e = blockIdx.x >> 8, f = blockIdx.x & 255;
    int t = threadIdx.x;
    __shared__ float wsh[256];
    __shared__ float red[256];
    __shared__ float sgs;
    const float* W = conv_W + (size_t)(l * NEXP + e) * DIM * DIM;  // [d][f]
    wsh[t] = W[t * DIM + f];
    __syncthreads();
    float v = 0.f;
    #pragma unroll 8
    for (int d2 = 0; d2 < DIM; d2++) v += C[d2 * DIM + t] * wsh[d2];  // C symmetric: column read
    float a_t = msum[t] * (1.f / (float)N_NODES);
    float qp  = wsh[t] * v;
    float ap  = a_t * wsh[t];
    red[t] = qp; __syncthreads();
    for (int off = 128; off; off >>= 1) { if (t < off) red[t] += red[t + off]; __syncthreads(); }
    float q = red[0];                       // only t==0 uses it
    red[t] = ap; __syncthreads();
    for (int off = 128; off; off >>= 1) { if (t < off) red[t] += red[t + off]; __syncthreads(); }
    if (t == 0) {
        float aw  = red[0];
        float var = q * (1.f / (float)N_NODES) - aw * aw;
        var = fmaxf(var, 0.f);
        float sg = bn_gamma[(l * NEXP + e) * DIM + f] * rsqrtf(var + BN_EPS);
        sgs = sg;
        shiftb[e * DIM + f] = bn_beta[(l * NEXP + e) * DIM + f] - aw * sg;
    }
    __syncthreads();
    float w = wsh[t] * sgs;                 // == conv_W[t*256+f] * sg (k_wscale's value)
    unsigned short hi, lo;
    bf16split(w, hi, lo);
    size_t basep = ((size_t)e * 256 + f) * 512;
    Wpk[basep + t]       = hi;
    Wpk[basep + 256 + t] = lo;
}

// ---------------------------------------------------------------- pair-bucketed MoE GEMM via MFMA
// Split-bf16 x4 terms x2 experts = 64 K-steps of mfma_f32_16x16x32_bf16.
// r8-verified schedule: As2 ping-pong + 1 barrier/stage; Wt wave-private
// single-buffer. Numerics identical to baseline.
// out = ga*z_a + gb*z_b + ga*shA + gb*shB; ratio trick: acc = (ga/gb)*z_a + z_b, x gb at end.
// A-frag: A[m=lane&15][k=quad*8+j]; B-frag: B[k=quad*8+j][n=lane&15]; D: col=lane&15,row=quad*4+reg.
__global__ __launch_bounds__(256) void k_moe(const unsigned short* __restrict__ Apk,
                                             const unsigned short* __restrict__ Wpk,
                                             const float* __restrict__ shiftb,
                                             const int* __restrict__ gcount,
                                             const int* __restrict__ bnode,
                                             const float* __restrict__ gaN,
                                             const float* __restrict__ gbN,
                                             float* __restrict__ hout) {
    __shared__ short As2[2][64][40];  // ping-pong; pad 40: 80B row stride (16B-aligned)
    __shared__ short Wt[256][40];     // single-buffer, wave-private quarters
    __shared__ int   nds[64];
    __shared__ float gA[64], gB[64];
    __shared__ float shc[2][256];
    int p    = blockIdx.y;
    int cnt  = gcount[p];
    int base = blockIdx.x * 64;
    if (base >= cnt) return;
    const int eaT[6] = {0,0,0,1,1,2};
    const int ebT[6] = {1,2,3,2,3,3};
    int ea = eaT[p], eb = ebT[p];
    int t  = threadIdx.x;
    if (t < 64) {
        int idx = base + t;
        if (idx < cnt) {
            int n = bnode[p * N_NODES + idx];
            nds[t] = n; gA[t] = gaN[n]; gB[t] = gbN[n];
        } else { nds[t] = -1; gA[t] = 0.f; gB[t] = 0.f; }
    }
    if (t < 128) {   // stage both shift rows
        int which = t >> 6, c = t & 63;
        int e = which ? eb : ea;
        ((float4*)shc[which])[c] = ((const float4*)(shiftb + e * DIM))[c];
    }
    __syncthreads();

    // staging roles
    int rA   = t >> 2;            // A row 0..63 (all waves cooperate on As2)
    int cA8  = (t & 3) * 8;       // 8 ushorts within 32-k chunk
    int wv   = t >> 6, wl = t & 63;
    int wrow = wv * 64 + (wl >> 2);   // own-quarter W row; +16i covers 64 rows/wave
    int wc8  = (wl & 3) * 8;

    int nrow = nds[rA];
    const unsigned short* arow = Apk + (size_t)(nrow < 0 ? 0 : nrow) * 512;

    // prefetch stage 0: expert ea, term hh, kc=0 -> aoff=0, woff=0
    u16x8 areg = {0,0,0,0,0,0,0,0};
    if (nrow >= 0) areg = *(const u16x8*)(arow + cA8);
    u16x8 wreg0, wreg1, wreg2, wreg3;
    {
        const unsigned short* wb = Wpk + ((size_t)ea * 256 + wrow) * 512 + wc8;
        wreg0 = *(const u16x8*)(wb);
        wreg1 = *(const u16x8*)(wb + (size_t)16 * 512);
        wreg2 = *(const u16x8*)(wb + (size_t)32 * 512);
        wreg3 = *(const u16x8*)(wb + (size_t)48 * 512);
    }

    int lane = t & 63, quad = lane >> 4, l16 = lane & 15;
    f32x4 acc[4][4];
    #pragma unroll
    for (int a = 0; a < 4; a++)
        #pragma unroll
        for (int b = 0; b < 4; b++) { f32x4 z = {0.f,0.f,0.f,0.f}; acc[a][b] = z; }

    for (int s = 0; s < 64; s++) {
        int buf = s & 1;
        *(u16x8*)&As2[buf][rA][cA8]   = areg;
        *(u16x8*)&Wt[wrow     ][wc8]  = wreg0;
        *(u16x8*)&Wt[wrow + 16][wc8]  = wreg1;
        *(u16x8*)&Wt[wrow + 32][wc8]  = wreg2;
        *(u16x8*)&Wt[wrow + 48][wc8]  = wreg3;
        __syncthreads();               // single barrier per stage
        if (s < 63) {                  // prefetch next stage (in flight during MFMA)
            int s1   = s + 1;
            int esel = s1 >> 5;                    // 0: ea, 1: eb
            int t2   = (s1 >> 3) & 3;              // term: hh, hl, lh, ll
            int kc   = (s1 & 7) * 32;
            int aoff = (t2 >= 2 ? 256 : 0) + kc;   // Ahi for t2 0,1; Alo for 2,3
            int woff = ((t2 & 1) ? 256 : 0) + kc;  // Whi for even t2, Wlo for odd
            u16x8 z8 = {0,0,0,0,0,0,0,0};
            areg = z8;
            if (nrow >= 0) areg = *(const u16x8*)(arow + aoff + cA8);
            const unsigned short* wb = Wpk
                + ((size_t)(esel ? eb : ea) * 256 + wrow) * 512 + woff + wc8;
            wreg0 = *(const u16x8*)(wb);
            wreg1 = *(const u16x8*)(wb + (size_t)16 * 512);
            wreg2 = *(const u16x8*)(wb + (size_t)32 * 512);
            wreg3 = *(const u16x8*)(wb + (size_t)48 * 512);
        }
        // compute: 16 MFMA on this 32-k chunk
        s16x8 af[4], bfr[4];
        #pragma unroll
        for (int rt = 0; rt < 4; rt++)
            af[rt] = *(const s16x8*)&As2[buf][rt * 16 + l16][quad * 8];
        #pragma unroll
        for (int ct = 0; ct < 4; ct++)
            bfr[ct] = *(const s16x8*)&Wt[wv * 64 + ct * 16 + l16][quad * 8];
        #pragma unroll
        for (int rt = 0; rt < 4; rt++)
            #pragma unroll
            for (int ct = 0; ct < 4; ct++)
                acc[rt][ct] = __builtin_amdgcn_mfma_f32_16x16x32_bf16(
                                  af[rt], bfr[ct], acc[rt][ct], 0, 0, 0);
        if (s == 31) {   // expert-a done: acc *= ga/gb per row
            #pragma unroll
            for (int rt = 0; rt < 4; rt++)
                #pragma unroll
                for (int r = 0; r < 4; r++) {
                    int row = rt * 16 + quad * 4 + r;
                    float ratio = gA[row] / fmaxf(gB[row], 1e-30f);
                    #pragma unroll
                    for (int ct = 0; ct < 4; ct++) acc[rt][ct][r] *= ratio;
                }
        }
    }

    // epilogue: out = gb*acc + ga*shA + gb*shB; h = v + relu(v)
    #pragma unroll
    for (int rt = 0; rt < 4; rt++)
        #pragma unroll
        for (int r = 0; r < 4; r++) {
            int row = rt * 16 + quad * 4 + r;
            int n = nds[row];
            if (n < 0) continue;
            float gaL = gA[row];
            float gbL = fmaxf(gB[row], 1e-30f);
            #pragma unroll
            for (int ct = 0; ct < 4; ct++) {
                int col = wv * 64 + ct * 16 + l16;
                float v = gbL * acc[rt][ct][r] + gaL * shc[0][col] + gbL * shc[1][col];
                hout[(size_t)n * DIM + col] = v + fmaxf(v, 0.f);
            }
        }
}

// ================================================================ host
extern "C" void kernel_launch(void* const* d_in, const int* in_sizes, int n_in,
                              void* d_out, int out_size, void* d_ws, size_t ws_size,
                              hipStream_t stream) {
    const int*   x        = (const int*)d_in[0];
    const int*   ei       = (const int*)d_in[1];
    const float* emb      = (const float*)d_in[2];
    const float* w_gate   = (const float*)d_in[3];
    const float* conv_W   = (const float*)d_in[4];
    // conv_b (d_in[5]) cancels exactly in the BN fold — unused
    const float* bn_gamma = (const float*)d_in[6];
    const float* bn_beta  = (const float*)d_in[7];
    float* out = (float*)d_out;

    const int* src = ei;
    const int* dst = ei + NEDGE;

    char* ws = (char*)d_ws;
    size_t off = 0;
    auto alloc = [&](size_t bytes) -> void* {
        void* p = ws + off;
        off += (bytes + 255) & ~(size_t)255;
        return p;
    };
    float*          h       = (float*)alloc((size_t)N_NODES * DIM * 4);
    float*          agg     = (float*)alloc((size_t)N_NODES * DIM * 4);
    unsigned short* Apk     = (unsigned short*)alloc((size_t)N_NODES * 512 * 2);
    int*            cnt_out = (int*)  alloc((size_t)N_NODES * 4);
    int*            cnt_in  = (int*)  alloc((size_t)N_NODES * 4);
    float*          nsrc    = (float*)alloc((size_t)N_NODES * 4);
    float*          ndst    = (float*)alloc((size_t)N_NODES * 4);
    int*            offs    = (int*)  alloc((size_t)(N_NODES + 1) * 4);
    int*            cursor  = (int*)  alloc((size_t)N_NODES * 4);
    int*            csr_s   = (int*)  alloc((size_t)NEDGE * 4);
    int*            pid     = (int*)  alloc((size_t)N_NODES * 4);
    float*          gaN     = (float*)alloc((size_t)N_NODES * 4);
    float*          gbN     = (float*)alloc((size_t)N_NODES * 4);
    int*            gcount  = (int*)  alloc(6 * 4);
    int*            bnode   = (int*)  alloc((size_t)6 * N_NODES * 4);
    float*          Cp      = (float*)alloc((size_t)GSL * NPAIR * 4096 * 4);
    float*          Cm      = (float*)alloc((size_t)DIM * DIM * 4);
    float*          msum_p  = (float*)alloc((size_t)250 * 256 * 4);
    float*          msum    = (float*)alloc((size_t)DIM * 4);
    float*          shiftb  = (float*)alloc((size_t)NEXP * DIM * 4);
    unsigned short* Wpk     = (unsigned short*)alloc((size_t)NEXP * DIM * 512 * 2);
    (void)ws_size; (void)in_sizes; (void)n_in; (void)out_size;

    // ---- graph structure (per call; inputs are restored every call)
    // single memset covers cnt_out (padded) + cnt_in: adjacent allocations
    size_t cnt_span = (size_t)((char*)cnt_in - (char*)cnt_out) + (size_t)N_NODES * 4;
    hipMemsetAsync(cnt_out, 0, cnt_span, stream);
    k_deg <<<(NEDGE + 255) / 256, 256, 0, stream>>>(src, dst, cnt_out, cnt_in);
    k_scan<<<1, 1024, 0, stream>>>(cnt_in, cnt_out, offs, cursor, nsrc, ndst);
    k_fill<<<(NEDGE + 255) / 256, 256, 0, stream>>>(src, dst, cursor, csr_s);
    k_emb <<<(N_NODES * 64 + 255) / 256, 256, 0, stream>>>(x, (const float4*)emb, (float4*)h);

    for (int l = 0; l < NLAYER; l++) {
        float* hout = (l == NLAYER - 1) ? out : h;   // k_moe reads only Apk+buckets: in-place OK

        k_gate<<<N_NODES / 4, 256, 0, stream>>>((const float4*)h,
                (const float4*)(w_gate + (size_t)l * DIM * NEXP), pid, gaN, gbN, gcount);
        k_agg<<<N_NODES / 4, 256, 0, stream>>>((const float4*)h, offs, csr_s, nsrc,
                ndst, (float4*)agg);
        k_gram<<<dim3(GSL, 16), 256, 0, stream>>>(agg, Cp, pid, gcount, bnode,
                                                  Apk, msum_p);
        k_red<<<257, 256, 0, stream>>>(msum_p, msum, Cp, Cm);
        k_stats<<<NEXP * DIM, 256, 0, stream>>>(Cm, msum, conv_W, bn_gamma, bn_beta,
                                                shiftb, Wpk, l);
        k_moe<<<dim3((N_NODES + 63) / 64, 6), 256, 0, stream>>>(Apk, Wpk, shiftb,
                gcount, bnode, gaN, gbN, hout);
    }
}

// Round 11
// 1759.432 us; speedup vs baseline: 1.0690x; 1.0690x over previous
//
#include <hip/hip_runtime.h>
#include <hip/hip_bf16.h>

#define N_NODES 50000
#define DIM     256
#define NEXP    4
#define NLAYER  3
#define NEDGE   1600000
#define BN_EPS  1e-5f

typedef __attribute__((ext_vector_type(8))) short          s16x8;
typedef __attribute__((ext_vector_type(8))) unsigned short u16x8;
typedef __attribute__((ext_vector_type(4))) float          f32x4;

// ---------------------------------------------------------------- utilities
static __device__ __forceinline__ float wave_reduce(float v) {
    #pragma unroll
    for (int off = 32; off; off >>= 1) v += __shfl_xor(v, off, 64);
    return v;
}

// split f32 into bf16 hi + bf16 lo (RNE); x ≈ hi + lo with |resid| <= 2^-18 |x|
static __device__ __forceinline__ void bf16split(float x, unsigned short& hi,
                                                 unsigned short& lo) {
    unsigned xb = __float_as_uint(x);
    unsigned hb = (xb + 0x7FFFu + ((xb >> 16) & 1u)) & 0xFFFF0000u;
    float hif = __uint_as_float(hb);
    float l  = x - hif;                       // exact (Sterbenz)
    unsigned lb2 = __float_as_uint(l);
    unsigned lb  = (lb2 + 0x7FFFu + ((lb2 >> 16) & 1u)) >> 16;
    hi = (unsigned short)(hb >> 16);
    lo = (unsigned short)lb;
}

// ---------------------------------------------------------------- degrees
__global__ void k_deg(const int* __restrict__ src, const int* __restrict__ dst,
                      int* __restrict__ cnt_out, int* __restrict__ cnt_in) {
    int i = blockIdx.x * 256 + threadIdx.x;
    if (i < NEDGE) {
        atomicAdd(&cnt_out[src[i]], 1);
        atomicAdd(&cnt_in[dst[i]], 1);
    }
}

// exclusive scan of cnt_in -> offs (N+1), copy to cursor.
// ROUND-11: reverted to the r9 lean body. r10's norm-fusion here made this
// single-block kernel 241us (top dispatch!) — one CU at 0.17% occupancy doing
// 50K rsqrt+stores serially. LESSON: never move parallel work into a
// single-block kernel (gap ~20us << 1-CU serial cost). Norm lives in k_fill now.
__global__ __launch_bounds__(1024) void k_scan(const int* __restrict__ cnt_in,
                                               int* __restrict__ offs,
                                               int* __restrict__ cursor) {
    __shared__ int ps[1024];
    const int CH = 49;                       // 1024*49 = 50176 >= 50000
    int t = threadIdx.x;
    int base = t * CH;
    int s = 0;
    for (int k = 0; k < CH; k++) { int i = base + k; if (i < N_NODES) s += cnt_in[i]; }
    ps[t] = s; __syncthreads();
    for (int off = 1; off < 1024; off <<= 1) {
        int v = ps[t];
        int u = (t >= off) ? ps[t - off] : 0;
        __syncthreads();
        ps[t] = v + u;
        __syncthreads();
    }
    int run = (t == 0) ? 0 : ps[t - 1];
    for (int k = 0; k < CH; k++) {
        int i = base + k;
        if (i < N_NODES) { offs[i] = run; cursor[i] = run; run += cnt_in[i]; }
    }
    if (t == 1023) offs[N_NODES] = ps[1023];
}

// csr fill; ROUND-11: also does k_norm's job (first 50000 threads) — identical
// rsqrtf(fmaxf(...)) formulas on final counts (k_deg completed) -> bit-exact;
// nsrc/ndst first consumed by k_agg, two dispatches later. Parallel (6250
// blocks), unlike the failed r10 single-block fusion.
__global__ void k_fill(const int* __restrict__ src, const int* __restrict__ dst,
                       int* __restrict__ cursor, int* __restrict__ csr_s,
                       const int* __restrict__ cnt_out, const int* __restrict__ cnt_in,
                       float* __restrict__ nsrc, float* __restrict__ ndst) {
    int i = blockIdx.x * 256 + threadIdx.x;
    if (i < N_NODES) {
        nsrc[i] = rsqrtf(fmaxf((float)cnt_out[i], 1.f));
        ndst[i] = rsqrtf(fmaxf((float)cnt_in[i], 1.f));
    }
    if (i < NEDGE) {
        int s = src[i], d = dst[i];
        int pos = atomicAdd(&cursor[d], 1);   // order varies per run -> k_agg must be
        csr_s[pos] = s;                       // order-invariant (fixed-point acc)
    }
}

// ---------------------------------------------------------------- embedding
__global__ void k_emb(const int* __restrict__ x, const float4* __restrict__ emb4,
                      float4* __restrict__ h4) {
    int i = blockIdx.x * 256 + threadIdx.x;   // N*64 float4s
    if (i < N_NODES * 64) {
        int n = i >> 6, c = i & 63;
        h4[i] = emb4[x[n] * 64 + c];
    }
}

// ---------------------------------------------------------------- gating: pid + (ga,gb) per node
// pair ids: (0,1)=0 (0,2)=1 (0,3)=2 (1,2)=3 (1,3)=4 (2,3)=5; ga = gate of lower-index expert
// Also zeroes gcount (block 0) — consumed 2 dispatches later (k_gram's bucket
// branch), stream order guarantees completion. Replaces the gcount memset.
__global__ void k_gate(const float4* __restrict__ h4, const float4* __restrict__ wg4,
                       int* __restrict__ pid, float* __restrict__ gaN,
                       float* __restrict__ gbN, int* __restrict__ gcount) {
    if (blockIdx.x == 0 && threadIdx.x < 6) gcount[threadIdx.x] = 0;
    int n    = blockIdx.x * 4 + (threadIdx.x >> 6);
    int lane = threadIdx.x & 63;
    if (n >= N_NODES) return;
    float4 hv = h4[n * 64 + lane];
    const float* hp = (const float*)&hv;
    float4 acc = {0.f, 0.f, 0.f, 0.f};
    #pragma unroll
    for (int j = 0; j < 4; j++) {
        float4 w = wg4[lane * 4 + j];   // w_gate[l][d][0..3]
        acc.x += hp[j] * w.x; acc.y += hp[j] * w.y;
        acc.z += hp[j] * w.z; acc.w += hp[j] * w.w;
    }
    acc.x = wave_reduce(acc.x); acc.y = wave_reduce(acc.y);
    acc.z = wave_reduce(acc.z); acc.w = wave_reduce(acc.w);
    if (lane == 0) {
        float lg[4] = {acc.x, acc.y, acc.z, acc.w};
        int e1 = 0;
        #pragma unroll
        for (int e = 1; e < 4; e++) if (lg[e] > lg[e1]) e1 = e;   // ties -> lower idx (top_k)
        int e2 = -1;
        #pragma unroll
        for (int e = 0; e < 4; e++) {
            if (e == e1) continue;
            if (e2 < 0 || lg[e] > lg[e2]) e2 = e;
        }
        float v1 = lg[e1], v2 = lg[e2];
        float g2 = 1.f / (1.f + expf(v1 - v2));   // softmax over {v1,v2}
        float g1 = 1.f - g2;
        int a = min(e1, e2), b = max(e1, e2);
        float ga = (e1 < e2) ? g1 : g2;
        float gb = (e1 < e2) ? g2 : g1;
        int p = (a == 0) ? (b - 1) : ((a == 1) ? (b + 1) : (b + 2));
        pid[n] = p; gaN[n] = ga; gbN[n] = gb;
    }
}

// ---------------------------------------------------------------- aggregation (one wave / dst)
// R0-BASELINE BODY (thrice-verified; fastest variant: ~221us, VGPR 24, occ 76%).
// k_agg floor ~220us: r4 (unroll-4: no change), r5 (f64: VALU 73->28%, no change),
// r6 (XCD-slice: 4.3x WORSE) bracket it as L3->L2 fill-path bound for this
// random gather. SINGLE-OUTPUT ONLY: adding extra outputs here fails
// deterministically (4-for-4: rounds 0,1,2,7) — any multi-output fusion into
// k_agg is BANNED.
// DETERMINISM: csr order varies per run (atomic fill). int64 fixed-point
// (quantum 2^-32) accumulate: integer addition is order-invariant -> h is
// bit-identical across runs regardless of atomic scheduling.
__global__ void k_agg(const float4* __restrict__ h4,
                      const int* __restrict__ offs,
                      const int* __restrict__ csr_s, const float* __restrict__ nsrc,
                      const float* __restrict__ ndst,
                      float4* __restrict__ agg4) {
    const float S  = 4294967296.0f;        // 2^32 (exact exponent shift on w)
    const float SI = 1.0f / 4294967296.0f;
    int n    = blockIdx.x * 4 + (threadIdx.x >> 6);
    int lane = threadIdx.x & 63;
    if (n >= N_NODES) return;
    int beg = offs[n], end = offs[n + 1];
    long long ax = 0, ay = 0, az = 0, aw = 0;
    int j = beg;
    for (; j + 1 < end; j += 2) {          // unroll-2: two independent gathers in flight
        int   s0 = csr_s[j],     s1 = csr_s[j + 1];
        float w0 = nsrc[s0] * S, w1 = nsrc[s1] * S;
        float4 a = h4[(size_t)s0 * 64 + lane];
        float4 b = h4[(size_t)s1 * 64 + lane];
        ax += (long long)(w0 * a.x) + (long long)(w1 * b.x);
        ay += (long long)(w0 * a.y) + (long long)(w1 * b.y);
        az += (long long)(w0 * a.z) + (long long)(w1 * b.z);
        aw += (long long)(w0 * a.w) + (long long)(w1 * b.w);
    }
    if (j < end) {
        int   s0 = csr_s[j];
        float w0 = nsrc[s0] * S;
        float4 a = h4[(size_t)s0 * 64 + lane];
        ax += (long long)(w0 * a.x); ay += (long long)(w0 * a.y);
        az += (long long)(w0 * a.z); aw += (long long)(w0 * a.w);
    }
    float nd = ndst[n] * SI;
    float4 o;
    o.x = nd * (float)ax; o.y = nd * (float)ay;
    o.z = nd * (float)az; o.w = nd * (float)aw;
    agg4[n * 64 + lane] = o;
}

// ---------------------------------------------------------------- Gram + pack/colsum/bucket mega-kernel
// grid.y = 16. pr<10: Gram pair-tile blocks (verbatim body -> Cp bit-identical).
// pr>=10: the pcs body (250 blocks, CH=200, same mapping and add order ->
// msum_p/Apk bit-identical) plus k_bucket's two-level counting for the block's
// own 200-node range (bucket order varies per run — tolerated: k_moe output is
// per-node independent of tile mates).
#define GSL   48     // k-slices
#define GCH   1056   // rows per slice: 48*1056 = 50688 >= 50000 (multiple of 16)
#define NPAIR 10
__global__ __launch_bounds__(256) void k_gram(const float* __restrict__ agg,
                                              float* __restrict__ Cp,
                                              const int* __restrict__ pid,
                                              int* __restrict__ gcount,
                                              int* __restrict__ bnode,
                                              unsigned short* __restrict__ Apk,
                                              float* __restrict__ msum_p) {
    __shared__ float LA[16][64];
    __shared__ float LB[16][64];
    __shared__ int cnt6[6], base6[6];
    int t  = threadIdx.x;
    int pr = blockIdx.y;            // 0..9: gram pair; 10..15: pcs/bucket chunk
    if (pr >= 10) {
        int gid = blockIdx.x * 6 + (pr - 10);   // 0..287
        if (gid >= 250) return;
        const int CH = 200;                     // 250*200 = 50000 exact
        int n0 = gid * CH;
        // ---- bucket (k_bucket two-level pattern over this block's node range)
        if (t < 6) cnt6[t] = 0;
        __syncthreads();
        int p = 0, pos = 0;
        bool valid = (t < CH);
        if (valid) { p = pid[n0 + t]; pos = atomicAdd(&cnt6[p], 1); }
        __syncthreads();
        if (t < 6) base6[t] = atomicAdd(&gcount[t], cnt6[t]);
        __syncthreads();
        if (valid) bnode[p * N_NODES + base6[p] + pos] = n0 + t;
        // ---- pack + column-sum
        float s = 0.f;
        for (int r = 0; r < CH; r++) {
            int n = n0 + r;
            float v = agg[(size_t)n * DIM + t];
            s += v;
            unsigned short hi, lo;
            bf16split(v, hi, lo);
            Apk[(size_t)n * 512 + t]       = hi;
            Apk[(size_t)n * 512 + 256 + t] = lo;
        }
        msum_p[gid * 256 + t] = s;
        return;
    }
    const int tiT[NPAIR] = {0,0,0,0,1,1,1,2,2,3};
    const int tjT[NPAIR] = {0,1,2,3,1,2,3,2,3,3};
    int sl = blockIdx.x;            // k-slice
    int ti = tiT[pr], tj = tjT[pr];
    int tx = t & 15, ty = t >> 4;
    float acc[4][4] = {};
    int nbase = sl * GCH;
    const float4* agg4 = (const float4*)agg;
    for (int s0 = 0; s0 < GCH; s0 += 16) {
        int r = ty;                  // 16 rows staged, one per thread group
        int n = nbase + s0 + r;
        float4 va = {0.f, 0.f, 0.f, 0.f}, vb = {0.f, 0.f, 0.f, 0.f};
        if (n < N_NODES) {
            va = agg4[n * 64 + ti * 16 + tx];
            vb = agg4[n * 64 + tj * 16 + tx];
        }
        __syncthreads();
        *(float4*)&LA[r][tx * 4] = va;
        *(float4*)&LB[r][tx * 4] = vb;
        __syncthreads();
        #pragma unroll
        for (int rr = 0; rr < 16; rr++) {
            float4 a = *(const float4*)&LA[rr][tx * 4];
            float4 b = *(const float4*)&LB[rr][ty * 4];
            const float* af = (const float*)&a;
            const float* bf = (const float*)&b;
            #pragma unroll
            for (int i = 0; i < 4; i++)
                #pragma unroll
                for (int j = 0; j < 4; j++)
                    acc[i][j] += af[i] * bf[j];
        }
    }
    float* Cb = Cp + ((size_t)(sl * NPAIR + pr)) * 4096;
    #pragma unroll
    for (int i = 0; i < 4; i++) {
        float4 v; v.x = acc[i][0]; v.y = acc[i][1]; v.z = acc[i][2]; v.w = acc[i][3];
        *(float4*)&Cb[(tx * 4 + i) * 64 + ty * 4] = v;
    }
}

// ---------------------------------------------------------------- fused reductions
// Block 0 = msumred body verbatim; blocks 1..256 = gred body verbatim with
// gid = (bid-1)*256 + t. Outputs independent; add orders unchanged -> bit-exact.
__global__ void k_red(const float* __restrict__ msum_p, float* __restrict__ msum,
                      const float* __restrict__ Cp, float* __restrict__ Cm) {
    int t = threadIdx.x;
    if (blockIdx.x == 0) {
        float s = 0.f;
        for (int b = 0; b < 250; b++) s += msum_p[b * 256 + t];
        msum[t] = s;
        return;
    }
    int gid = (blockIdx.x - 1) * 256 + t;        // 65536
    int i = gid >> 8, j = gid & 255;
    int a = i >> 6, b = j >> 6, ii = i & 63, jj = j & 63;
    int ro = ii, co = jj;
    if (a > b) { int tmp = a; a = b; b = tmp; ro = jj; co = ii; }   // symmetric reconstruct
    int pr = (a == 0) ? b : ((a == 1) ? 3 + b : ((a == 2) ? 5 + b : 6 + b));
    const float* p = Cp + (size_t)pr * 4096 + ro * 64 + co;
    float s = 0.f;
    #pragma unroll 8
    for (int sl = 0; sl < GSL; sl++) s += p[(size_t)sl * NPAIR * 4096];
    Cm[gid] = s;
}

// ---------------------------------------------------------------- BN stats -> shift + packed W
// k_wscale fused in. wsh[t] = W[t][f] is already staged in LDS; after sg is
// computed it is broadcast via LDS and every thread writes
// Wpk[(e*256+f)*512 + t] = bf16split(wsh[t]*sg) — the IDENTICAL float product
// k_wscale computed -> Wpk bit-identical. scaleb buffer eliminated.
__global__ __launch_bounds__(256) void k_stats(const float* __restrict__ C,
                                               const float* __restrict__ msum,
                                               const float* __restrict__ conv_W,
                                               const float* __restrict__ bn_gamma,
                                               const float* __restrict__ bn_beta,
                                               float* __restrict__ shiftb,
                                               unsigned short* __restrict__ Wpk,
                                               int l) {
    int e = blockIdx.x >> 8, f = blockIdx.x & 255;
    int t = threadIdx.x;
    __shared__ float wsh[256];
    __shared__ float red[256];
    __shared__ float sgs;
    const float* W = conv_W + (size_t)(l * NEXP + e) * DIM * DIM;  // [d][f]
    wsh[t] = W[t * DIM + f];
    __syncthreads();
    float v = 0.f;
    #pragma unroll 8
    for (int d2 = 0; d2 < DIM; d2++) v += C[d2 * DIM + t] * wsh[d2];  // C symmetric: column read
    float a_t = msum[t] * (1.f / (float)N_NODES);
    float qp  = wsh[t] * v;
    float ap  = a_t * wsh[t];
    red[t] = qp; __syncthreads();
    for (int off = 128; off; off >>= 1) { if (t < off) red[t] += red[t + off]; __syncthreads(); }
    float q = red[0];                       // only t==0 uses it
    red[t] = ap; __syncthreads();
    for (int off = 128; off; off >>= 1) { if (t < off) red[t] += red[t + off]; __syncthreads(); }
    if (t == 0) {
        float aw  = red[0];
        float var = q * (1.f / (float)N_NODES) - aw * aw;
        var = fmaxf(var, 0.f);
        float sg = bn_gamma[(l * NEXP + e) * DIM + f] * rsqrtf(var + BN_EPS);
        sgs = sg;
        shiftb[e * DIM + f] = bn_beta[(l * NEXP + e) * DIM + f] - aw * sg;
    }
    __syncthreads();
    float w = wsh[t] * sgs;                 // == conv_W[t*256+f] * sg (k_wscale's value)
    unsigned short hi, lo;
    bf16split(w, hi, lo);
    size_t basep = ((size_t)e * 256 + f) * 512;
    Wpk[basep + t]       = hi;
    Wpk[basep + 256 + t] = lo;
}

// ---------------------------------------------------------------- pair-bucketed MoE GEMM via MFMA
// Split-bf16 x4 terms x2 experts = 64 K-steps of mfma_f32_16x16x32_bf16.
// r8-verified schedule: As2 ping-pong + 1 barrier/stage; Wt wave-private
// single-buffer. Numerics identical to baseline.
// out = ga*z_a + gb*z_b + ga*shA + gb*shB; ratio trick: acc = (ga/gb)*z_a + z_b, x gb at end.
// A-frag: A[m=lane&15][k=quad*8+j]; B-frag: B[k=quad*8+j][n=lane&15]; D: col=lane&15,row=quad*4+reg.
__global__ __launch_bounds__(256) void k_moe(const unsigned short* __restrict__ Apk,
                                             const unsigned short* __restrict__ Wpk,
                                             const float* __restrict__ shiftb,
                                             const int* __restrict__ gcount,
                                             const int* __restrict__ bnode,
                                             const float* __restrict__ gaN,
                                             const float* __restrict__ gbN,
                                             float* __restrict__ hout) {
    __shared__ short As2[2][64][40];  // ping-pong; pad 40: 80B row stride (16B-aligned)
    __shared__ short Wt[256][40];     // single-buffer, wave-private quarters
    __shared__ int   nds[64];
    __shared__ float gA[64], gB[64];
    __shared__ float shc[2][256];
    int p    = blockIdx.y;
    int cnt  = gcount[p];
    int base = blockIdx.x * 64;
    if (base >= cnt) return;
    const int eaT[6] = {0,0,0,1,1,2};
    const int ebT[6] = {1,2,3,2,3,3};
    int ea = eaT[p], eb = ebT[p];
    int t  = threadIdx.x;
    if (t < 64) {
        int idx = base + t;
        if (idx < cnt) {
            int n = bnode[p * N_NODES + idx];
            nds[t] = n; gA[t] = gaN[n]; gB[t] = gbN[n];
        } else { nds[t] = -1; gA[t] = 0.f; gB[t] = 0.f; }
    }
    if (t < 128) {   // stage both shift rows
        int which = t >> 6, c = t & 63;
        int e = which ? eb : ea;
        ((float4*)shc[which])[c] = ((const float4*)(shiftb + e * DIM))[c];
    }
    __syncthreads();

    // staging roles
    int rA   = t >> 2;            // A row 0..63 (all waves cooperate on As2)
    int cA8  = (t & 3) * 8;       // 8 ushorts within 32-k chunk
    int wv   = t >> 6, wl = t & 63;
    int wrow = wv * 64 + (wl >> 2);   // own-quarter W row; +16i covers 64 rows/wave
    int wc8  = (wl & 3) * 8;

    int nrow = nds[rA];
    const unsigned short* arow = Apk + (size_t)(nrow < 0 ? 0 : nrow) * 512;

    // prefetch stage 0: expert ea, term hh, kc=0 -> aoff=0, woff=0
    u16x8 areg = {0,0,0,0,0,0,0,0};
    if (nrow >= 0) areg = *(const u16x8*)(arow + cA8);
    u16x8 wreg0, wreg1, wreg2, wreg3;
    {
        const unsigned short* wb = Wpk + ((size_t)ea * 256 + wrow) * 512 + wc8;
        wreg0 = *(const u16x8*)(wb);
        wreg1 = *(const u16x8*)(wb + (size_t)16 * 512);
        wreg2 = *(const u16x8*)(wb + (size_t)32 * 512);
        wreg3 = *(const u16x8*)(wb + (size_t)48 * 512);
    }

    int lane = t & 63, quad = lane >> 4, l16 = lane & 15;
    f32x4 acc[4][4];
    #pragma unroll
    for (int a = 0; a < 4; a++)
        #pragma unroll
        for (int b = 0; b < 4; b++) { f32x4 z = {0.f,0.f,0.f,0.f}; acc[a][b] = z; }

    for (int s = 0; s < 64; s++) {
        int buf = s & 1;
        *(u16x8*)&As2[buf][rA][cA8]   = areg;
        *(u16x8*)&Wt[wrow     ][wc8]  = wreg0;
        *(u16x8*)&Wt[wrow + 16][wc8]  = wreg1;
        *(u16x8*)&Wt[wrow + 32][wc8]  = wreg2;
        *(u16x8*)&Wt[wrow + 48][wc8]  = wreg3;
        __syncthreads();               // single barrier per stage
        if (s < 63) {                  // prefetch next stage (in flight during MFMA)
            int s1   = s + 1;
            int esel = s1 >> 5;                    // 0: ea, 1: eb
            int t2   = (s1 >> 3) & 3;              // term: hh, hl, lh, ll
            int kc   = (s1 & 7) * 32;
            int aoff = (t2 >= 2 ? 256 : 0) + kc;   // Ahi for t2 0,1; Alo for 2,3
            int woff = ((t2 & 1) ? 256 : 0) + kc;  // Whi for even t2, Wlo for odd
            u16x8 z8 = {0,0,0,0,0,0,0,0};
            areg = z8;
            if (nrow >= 0) areg = *(const u16x8*)(arow + aoff + cA8);
            const unsigned short* wb = Wpk
                + ((size_t)(esel ? eb : ea) * 256 + wrow) * 512 + woff + wc8;
            wreg0 = *(const u16x8*)(wb);
            wreg1 = *(const u16x8*)(wb + (size_t)16 * 512);
            wreg2 = *(const u16x8*)(wb + (size_t)32 * 512);
            wreg3 = *(const u16x8*)(wb + (size_t)48 * 512);
        }
        // compute: 16 MFMA on this 32-k chunk
        s16x8 af[4], bfr[4];
        #pragma unroll
        for (int rt = 0; rt < 4; rt++)
            af[rt] = *(const s16x8*)&As2[buf][rt * 16 + l16][quad * 8];
        #pragma unroll
        for (int ct = 0; ct < 4; ct++)
            bfr[ct] = *(const s16x8*)&Wt[wv * 64 + ct * 16 + l16][quad * 8];
        #pragma unroll
        for (int rt = 0; rt < 4; rt++)
            #pragma unroll
            for (int ct = 0; ct < 4; ct++)
                acc[rt][ct] = __builtin_amdgcn_mfma_f32_16x16x32_bf16(
                                  af[rt], bfr[ct], acc[rt][ct], 0, 0, 0);
        if (s == 31) {   // expert-a done: acc *= ga/gb per row
            #pragma unroll
            for (int rt = 0; rt < 4; rt++)
                #pragma unroll
                for (int r = 0; r < 4; r++) {
                    int row = rt * 16 + quad * 4 + r;
                    float ratio = gA[row] / fmaxf(gB[row], 1e-30f);
                    #pragma unroll
                    for (int ct = 0; ct < 4; ct++) acc[rt][ct][r] *= ratio;
                }
        }
    }

    // epilogue: out = gb*acc + ga*shA + gb*shB; h = v + relu(v)
    #pragma unroll
    for (int rt = 0; rt < 4; rt++)
        #pragma unroll
        for (int r = 0; r < 4; r++) {
            int row = rt * 16 + quad * 4 + r;
            int n = nds[row];
            if (n < 0) continue;
            float gaL = gA[row];
            float gbL = fmaxf(gB[row], 1e-30f);
            #pragma unroll
            for (int ct = 0; ct < 4; ct++) {
                int col = wv * 64 + ct * 16 + l16;
                float v = gbL * acc[rt][ct][r] + gaL * shc[0][col] + gbL * shc[1][col];
                hout[(size_t)n * DIM + col] = v + fmaxf(v, 0.f);
            }
        }
}

// ================================================================ host
extern "C" void kernel_launch(void* const* d_in, const int* in_sizes, int n_in,
                              void* d_out, int out_size, void* d_ws, size_t ws_size,
                              hipStream_t stream) {
    const int*   x        = (const int*)d_in[0];
    const int*   ei       = (const int*)d_in[1];
    const float* emb      = (const float*)d_in[2];
    const float* w_gate   = (const float*)d_in[3];
    const float* conv_W   = (const float*)d_in[4];
    // conv_b (d_in[5]) cancels exactly in the BN fold — unused
    const float* bn_gamma = (const float*)d_in[6];
    const float* bn_beta  = (const float*)d_in[7];
    float* out = (float*)d_out;

    const int* src = ei;
    const int* dst = ei + NEDGE;

    char* ws = (char*)d_ws;
    size_t off = 0;
    auto alloc = [&](size_t bytes) -> void* {
        void* p = ws + off;
        off += (bytes + 255) & ~(size_t)255;
        return p;
    };
    float*          h       = (float*)alloc((size_t)N_NODES * DIM * 4);
    float*          agg     = (float*)alloc((size_t)N_NODES * DIM * 4);
    unsigned short* Apk     = (unsigned short*)alloc((size_t)N_NODES * 512 * 2);
    int*            cnt_out = (int*)  alloc((size_t)N_NODES * 4);
    int*            cnt_in  = (int*)  alloc((size_t)N_NODES * 4);
    float*          nsrc    = (float*)alloc((size_t)N_NODES * 4);
    float*          ndst    = (float*)alloc((size_t)N_NODES * 4);
    int*            offs    = (int*)  alloc((size_t)(N_NODES + 1) * 4);
    int*            cursor  = (int*)  alloc((size_t)N_NODES * 4);
    int*            csr_s   = (int*)  alloc((size_t)NEDGE * 4);
    int*            pid     = (int*)  alloc((size_t)N_NODES * 4);
    float*          gaN     = (float*)alloc((size_t)N_NODES * 4);
    float*          gbN     = (float*)alloc((size_t)N_NODES * 4);
    int*            gcount  = (int*)  alloc(6 * 4);
    int*            bnode   = (int*)  alloc((size_t)6 * N_NODES * 4);
    float*          Cp      = (float*)alloc((size_t)GSL * NPAIR * 4096 * 4);
    float*          Cm      = (float*)alloc((size_t)DIM * DIM * 4);
    float*          msum_p  = (float*)alloc((size_t)250 * 256 * 4);
    float*          msum    = (float*)alloc((size_t)DIM * 4);
    float*          shiftb  = (float*)alloc((size_t)NEXP * DIM * 4);
    unsigned short* Wpk     = (unsigned short*)alloc((size_t)NEXP * DIM * 512 * 2);
    (void)ws_size; (void)in_sizes; (void)n_in; (void)out_size;

    // ---- graph structure (per call; inputs are restored every call)
    // single memset covers cnt_out (padded) + cnt_in: adjacent allocations
    size_t cnt_span = (size_t)((char*)cnt_in - (char*)cnt_out) + (size_t)N_NODES * 4;
    hipMemsetAsync(cnt_out, 0, cnt_span, stream);
    k_deg <<<(NEDGE + 255) / 256, 256, 0, stream>>>(src, dst, cnt_out, cnt_in);
    k_scan<<<1, 1024, 0, stream>>>(cnt_in, offs, cursor);
    k_fill<<<(NEDGE + 255) / 256, 256, 0, stream>>>(src, dst, cursor, csr_s,
                                                    cnt_out, cnt_in, nsrc, ndst);
    k_emb <<<(N_NODES * 64 + 255) / 256, 256, 0, stream>>>(x, (const float4*)emb, (float4*)h);

    for (int l = 0; l < NLAYER; l++) {
        float* hout = (l == NLAYER - 1) ? out : h;   // k_moe reads only Apk+buckets: in-place OK

        k_gate<<<N_NODES / 4, 256, 0, stream>>>((const float4*)h,
                (const float4*)(w_gate + (size_t)l * DIM * NEXP), pid, gaN, gbN, gcount);
        k_agg<<<N_NODES / 4, 256, 0, stream>>>((const float4*)h, offs, csr_s, nsrc,
                ndst, (float4*)agg);
        k_gram<<<dim3(GSL, 16), 256, 0, stream>>>(agg, Cp, pid, gcount, bnode,
                                                  Apk, msum_p);
        k_red<<<257, 256, 0, stream>>>(msum_p, msum, Cp, Cm);
        k_stats<<<NEXP * DIM, 256, 0, stream>>>(Cm, msum, conv_W, bn_gamma, bn_beta,
                                                shiftb, Wpk, l);
        k_moe<<<dim3((N_NODES + 63) / 64, 6), 256, 0, stream>>>(Apk, Wpk, shiftb,
                gcount, bnode, gaN, gbN, hout);
    }
}